// Round 6
// baseline (6001.459 us; speedup 1.0000x reference)
//
#include <hip/hip_runtime.h>
#include <hip/hip_bf16.h>

// PathRNN: h_{t+1} = tanh(x_t + W_hh h_t), u = h, pos = u @ W_out^T
// B=128, T=1024, H=512.
// 8 WGs = 4 cohort-PAIRS x 2 N-halves (256 cols). 512 thr = 8 waves x 32 cols.
// Each WG serves TWO cohorts (2p, 2p+1) that SHARE the same W_hh registers
// (128 VGPR/lane). While cohort A's cross-WG handoff is in flight, cohort B
// computes -> the ~1500-cyc exchange latency is overlapped, not exposed.
// Exchange transport (PROVEN in round 4): self-tagged u64 words
// (2 adjacent-col bf16 + 32-bit step tag), 2-parity pub buffers, relaxed
// agent-scope atomics only (no fences, no flags); consumer polls the data.
// Publish-only-after-gather ordering makes overwrite-before-read impossible.
// Tags zeroed each launch for graph-replay determinism.

#define TT 1024
#define BB 128
#define HH 512

typedef short s16x8 __attribute__((ext_vector_type(8)));
typedef float f32x4 __attribute__((ext_vector_type(4)));
typedef unsigned int uint;
typedef unsigned short ushort_t;
typedef unsigned long long u64;
typedef uint u32x4 __attribute__((ext_vector_type(4)));

#define MFMA_B16(a, b, c) __builtin_amdgcn_mfma_f32_16x16x32_bf16((a), (b), (c), 0, 0, 0)
#define ALD(p) __hip_atomic_load((p), __ATOMIC_RELAXED, __HIP_MEMORY_SCOPE_AGENT)
#define AST(p, v) __hip_atomic_store((p), (v), __ATOMIC_RELAXED, __HIP_MEMORY_SCOPE_AGENT)

static __device__ __forceinline__ ushort_t bf16_rne(float f) {
  uint u = __float_as_uint(f);
  u += 0x7fffu + ((u >> 16) & 1u);
  return (ushort_t)(u >> 16);
}

static __device__ __forceinline__ float tanh_fast(float z) {
  float e = __expf(2.0f * z);
  return 1.0f - 2.0f * __builtin_amdgcn_rcpf(e + 1.0f);
}

static __device__ __forceinline__ s16x8 packW(const float* wp) {
  float4 lo = *(const float4*)wp;
  float4 hi = *(const float4*)(wp + 4);
  s16x8 s;
  s[0] = (short)bf16_rne(lo.x); s[1] = (short)bf16_rne(lo.y);
  s[2] = (short)bf16_rne(lo.z); s[3] = (short)bf16_rne(lo.w);
  s[4] = (short)bf16_rne(hi.x); s[5] = (short)bf16_rne(hi.y);
  s[6] = (short)bf16_rne(hi.z); s[7] = (short)bf16_rne(hi.w);
  return s;
}

static __device__ __forceinline__ uint tagmin4(u64 a, u64 b, u64 c, u64 d) {
  uint m0 = (uint)(a >> 32), m1 = (uint)(b >> 32);
  uint m2 = (uint)(c >> 32), m3 = (uint)(d >> 32);
  uint x = m0 < m1 ? m0 : m1;
  uint y = m2 < m3 ? m2 : m3;
  return x < y ? x : y;
}

// Epilogue + publish + own-LDS write + u-store for one cohort.
// acc0/acc1 = nt0/nt1 accumulators; vv = vel float2[4]; cc = global cohort id;
// ldsoff = this cohort's LDS base (0 or 32768).
#define EPI(cc, ldsoff, acc0, acc1, vv)                                          \
  {                                                                              \
    float uv0[4], uv1[4];                                                        \
    ushort_t hb0v[4], hb1v[4];                                                   \
    _Pragma("unroll") for (int r = 0; r < 4; ++r) {                              \
      float x0 = fmaf(vv[r].x, wih0[0], fmaf(vv[r].y, wih1[0], bs[0]));          \
      float x1 = fmaf(vv[r].x, wih0[1], fmaf(vv[r].y, wih1[1], bs[1]));          \
      uv0[r] = tanh_fast(x0 + acc0[r]);                                          \
      uv1[r] = tanh_fast(x1 + acc1[r]);                                          \
      hb0v[r] = bf16_rne(uv0[r]);                                                \
      hb1v[r] = bf16_rne(uv1[r]);                                                \
    }                                                                            \
    if (t < TT - 1) {                                                            \
      const bool odd = (l15 & 1) != 0;                                           \
      const uint rowbase = (uint)(kg * 4) + (odd ? 2u : 0u);                     \
      u64* dpb = pub + ((size_t)(nxt * 8 + (cc)) * 2 + half) * 2048;             \
      const u64 tw = (u64)(uint)(t + 1) << 32;                                   \
      const uint ldsb = (uint)(ldsoff) + (uint)nxt * 16384u;                     \
      _Pragma("unroll") for (int nt = 0; nt < 2; ++nt) {                         \
        const ushort_t* hb = nt ? hb1v : hb0v;                                   \
        uint a01p = (uint)hb[0] | ((uint)hb[1] << 16);                           \
        uint a23p = (uint)hb[2] | ((uint)hb[3] << 16);                           \
        uint b01p = __shfl_xor(a01p, 1);                                         \
        uint b23p = __shfl_xor(a23p, 1);                                         \
        uint eP = odd ? b23p : a01p;                                             \
        uint oP = odd ? a23p : b01p;                                             \
        uint pr0 = (eP & 0xFFFFu) | (oP << 16);                                  \
        uint pr1 = (eP >> 16) | (oP & 0xFFFF0000u);                              \
        uint cp = (uint)(w * 16) + ((uint)l15 >> 1) + (uint)(nt * 8);            \
        AST(dpb + rowbase * 128 + cp, (u64)pr0 | tw);                            \
        AST(dpb + (rowbase + 1) * 128 + cp, (u64)pr1 | tw);                      \
        uint cb = (uint)(n0 + nt * 16 + (l15 & ~1)) * 2u;                        \
        *(uint*)(hlds + ((ldsb + rowbase * 1024u + cb) ^                         \
                         ((rowbase & 7u) << 4))) = pr0;                          \
        *(uint*)(hlds + ((ldsb + (rowbase + 1) * 1024u + cb) ^                   \
                         (((rowbase + 1) & 7u) << 4))) = pr1;                    \
      }                                                                          \
    }                                                                            \
    _Pragma("unroll") for (int r = 0; r < 4; ++r) {                              \
      size_t ub = ((size_t)((cc)*16 + kg * 4 + r) * TT + t) * HH;                \
      __builtin_nontemporal_store(uv0[r], u_out + ub + n0 + l15);                \
      __builtin_nontemporal_store(uv1[r], u_out + ub + n0 + 16 + l15);           \
    }                                                                            \
  }

__global__ __launch_bounds__(512, 2) void rnn_kernel(
    const float* __restrict__ vel, const float* __restrict__ W_ih,
    const float* __restrict__ W_hh, const float* __restrict__ b_ih,
    const float* __restrict__ b_hh, float* __restrict__ u_out,
    u64* __restrict__ pub) {
  // LDS: [coh 2][par 2][row 16][col 512] bf16, byte ^ ((row&7)<<4). 64 KiB.
  __shared__ uint4 hlds_mem[4096];
  char* hlds = (char*)hlds_mem;

  const int tid = threadIdx.x;
  const int lane = tid & 63;
  const int w = tid >> 6;            // wave 0..7 -> 32-col tile
  const int pr_ = blockIdx.x >> 1;   // cohort pair 0..3
  const int half = blockIdx.x & 1;   // N half 0..1
  const int cA = pr_ * 2, cB = pr_ * 2 + 1;
  const int l15 = lane & 15;
  const int kg = lane >> 4;
  const int n0 = half * 256 + w * 32;
  const uint swz = ((uint)l15 & 7u) << 4;

  // ---- one-time: W_hh B-frags (shared by BOTH cohorts): q<8 local, q>=8 remote
  s16x8 wfr[2][16];
#pragma unroll
  for (int nt = 0; nt < 2; ++nt) {
    const float* wb = W_hh + (size_t)(n0 + nt * 16 + l15) * HH + kg * 8;
#pragma unroll
    for (int q = 0; q < 16; ++q) {
      int kt = (q < 8) ? (half * 8 + q) : ((1 - half) * 8 + (q - 8));
      wfr[nt][q] = packW(wb + kt * 32);
    }
  }
  float wih0[2], wih1[2], bs[2];
#pragma unroll
  for (int nt = 0; nt < 2; ++nt) {
    int n = n0 + nt * 16 + l15;
    wih0[nt] = W_ih[n * 2 + 0];
    wih1[nt] = W_ih[n * 2 + 1];
    bs[nt] = b_ih[n] + b_hh[n];
  }

  // ---- zero all 4 h buffers (h_0 = 0): 64 KB / 512 threads ----
  {
    uint4 z = {0u, 0u, 0u, 0u};
#pragma unroll
    for (int k = 0; k < 8; ++k) *(uint4*)(hlds + tid * 16 + k * 8192) = z;
  }
  __syncthreads();

  const f32x4 z4 = {0.f, 0.f, 0.f, 0.f};
  const uint lbyte = (uint)half * 512u;        // own K-half byte base in LDS row
  const uint rbyte = (uint)(1 - half) * 512u;  // peer K-half

  for (int t = 0; t < TT; ++t) {
    const int cur = t & 1;
    const int nxt = cur ^ 1;

    // ---- issue gathers for BOTH cohorts (4 tagged u64 each) ----
    const u64* spA = pub + ((size_t)(cur * 8 + cA) * 2 + (1 - half)) * 2048 + tid * 4;
    const u64* spB = pub + ((size_t)(cur * 8 + cB) * 2 + (1 - half)) * 2048 + tid * 4;
    u64 gA0 = 0, gA1 = 0, gA2 = 0, gA3 = 0, gB0 = 0, gB1 = 0, gB2 = 0, gB3 = 0;
    if (t > 0) {
      gA0 = ALD(spA); gA1 = ALD(spA + 1); gA2 = ALD(spA + 2); gA3 = ALD(spA + 3);
      gB0 = ALD(spB); gB1 = ALD(spB + 1); gB2 = ALD(spB + 2); gB3 = ALD(spB + 3);
    }

    // vel for this step (both cohorts)
    float2 vA[4], vB[4];
#pragma unroll
    for (int r = 0; r < 4; ++r) {
      vA[r] = *(const float2*)(vel + ((size_t)(cA * 16 + kg * 4 + r) * TT + t) * 2);
      vB[r] = *(const float2*)(vel + ((size_t)(cB * 16 + kg * 4 + r) * TT + t) * 2);
    }

    // ---- local-K MFMAs for A and B (overlap gather flight) ----
    f32x4 aA00 = z4, aA01 = z4, aA10 = z4, aA11 = z4;
    f32x4 aB00 = z4, aB01 = z4, aB10 = z4, aB11 = z4;
    const uint baseA = (uint)cur * 16384u + (uint)l15 * 1024u + (uint)kg * 16u;
    const uint baseB = baseA + 32768u;
#pragma unroll
    for (int q = 0; q < 8; ++q) {
      s16x8 fA = *(const s16x8*)(hlds + ((baseA + lbyte + (uint)q * 64u) ^ swz));
      s16x8 fB = *(const s16x8*)(hlds + ((baseB + lbyte + (uint)q * 64u) ^ swz));
      if (q & 1) {
        aA01 = MFMA_B16(fA, wfr[0][q], aA01); aA11 = MFMA_B16(fA, wfr[1][q], aA11);
        aB01 = MFMA_B16(fB, wfr[0][q], aB01); aB11 = MFMA_B16(fB, wfr[1][q], aB11);
      } else {
        aA00 = MFMA_B16(fA, wfr[0][q], aA00); aA10 = MFMA_B16(fA, wfr[1][q], aA10);
        aB00 = MFMA_B16(fB, wfr[0][q], aB00); aB10 = MFMA_B16(fB, wfr[1][q], aB10);
      }
    }

    // ---- wait for peer halves; place into LDS ----
    if (t > 0) {
      const uint tgt = (uint)t;
      while (tagmin4(gA0, gA1, gA2, gA3) < tgt) {
        gA0 = ALD(spA); gA1 = ALD(spA + 1); gA2 = ALD(spA + 2); gA3 = ALD(spA + 3);
      }
      asm volatile("" ::: "memory");
      {
        uint row = (uint)tid >> 5;
        uint ab = ((uint)cur * 16384u + row * 1024u + rbyte + ((uint)tid & 31u) * 16u) ^
                  ((row & 7u) << 4);
        u32x4 dw = {(uint)gA0, (uint)gA1, (uint)gA2, (uint)gA3};
        *(u32x4*)(hlds + ab) = dw;
      }
      while (tagmin4(gB0, gB1, gB2, gB3) < tgt) {
        gB0 = ALD(spB); gB1 = ALD(spB + 1); gB2 = ALD(spB + 2); gB3 = ALD(spB + 3);
      }
      asm volatile("" ::: "memory");
      {
        uint row = (uint)tid >> 5;
        uint ab = (32768u + (uint)cur * 16384u + row * 1024u + rbyte +
                   ((uint)tid & 31u) * 16u) ^ ((row & 7u) << 4);
        u32x4 dw = {(uint)gB0, (uint)gB1, (uint)gB2, (uint)gB3};
        *(u32x4*)(hlds + ab) = dw;
      }
    }
    __syncthreads();  // remote halves of h_t visible to all waves

    // ---- remote-K MFMAs for A and B ----
#pragma unroll
    for (int q = 8; q < 16; ++q) {
      s16x8 fA = *(const s16x8*)(hlds + ((baseA + rbyte + (uint)(q - 8) * 64u) ^ swz));
      s16x8 fB = *(const s16x8*)(hlds + ((baseB + rbyte + (uint)(q - 8) * 64u) ^ swz));
      if (q & 1) {
        aA01 = MFMA_B16(fA, wfr[0][q], aA01); aA11 = MFMA_B16(fA, wfr[1][q], aA11);
        aB01 = MFMA_B16(fB, wfr[0][q], aB01); aB11 = MFMA_B16(fB, wfr[1][q], aB11);
      } else {
        aA00 = MFMA_B16(fA, wfr[0][q], aA00); aA10 = MFMA_B16(fA, wfr[1][q], aA10);
        aB00 = MFMA_B16(fB, wfr[0][q], aB00); aB10 = MFMA_B16(fB, wfr[1][q], aB10);
      }
    }
    f32x4 accA0 = aA00 + aA01, accA1 = aA10 + aA11;
    f32x4 accB0 = aB00 + aB01, accB1 = aB10 + aB11;

    // ---- epilogue + publish + u-store, A first (its consumers wait) ----
    EPI(cA, 0, accA0, accA1, vA);
    EPI(cB, 32768, accB0, accB1, vB);

    if (t == TT - 1) break;
    __syncthreads();  // own halves of h_{t+1} visible for next round
  }
}

__global__ void init_kernel(u64* pub) {
  size_t idx = (size_t)blockIdx.x * 256 + threadIdx.x;
  __hip_atomic_store(&pub[idx], 0ull, __ATOMIC_RELAXED, __HIP_MEMORY_SCOPE_AGENT);
}

// pos[b,t,:] = u[b,t,:] @ W_out^T + b_out ; one wave per (b,t) row, BW-bound.
__global__ __launch_bounds__(256) void pos_kernel(const float* __restrict__ u,
                                                  const float* __restrict__ W_out,
                                                  const float* __restrict__ b_out,
                                                  float* __restrict__ pos) {
  int row = blockIdx.x * 4 + (threadIdx.x >> 6);
  int lane = threadIdx.x & 63;
  const float* ur = u + (size_t)row * HH + lane * 8;
  float4 u0 = *(const float4*)ur;
  float4 u1 = *(const float4*)(ur + 4);
  float4 w00 = *(const float4*)(W_out + lane * 8);
  float4 w01 = *(const float4*)(W_out + lane * 8 + 4);
  float4 w10 = *(const float4*)(W_out + HH + lane * 8);
  float4 w11 = *(const float4*)(W_out + HH + lane * 8 + 4);
  float p0 = u0.x * w00.x + u0.y * w00.y + u0.z * w00.z + u0.w * w00.w +
             u1.x * w01.x + u1.y * w01.y + u1.z * w01.z + u1.w * w01.w;
  float p1 = u0.x * w10.x + u0.y * w10.y + u0.z * w10.z + u0.w * w10.w +
             u1.x * w11.x + u1.y * w11.y + u1.z * w11.z + u1.w * w11.w;
#pragma unroll
  for (int off = 32; off; off >>= 1) {
    p0 += __shfl_xor(p0, off);
    p1 += __shfl_xor(p1, off);
  }
  if (lane == 0) {
    pos[(size_t)row * 2 + 0] = p0 + b_out[0];
    pos[(size_t)row * 2 + 1] = p1 + b_out[1];
  }
}

extern "C" void kernel_launch(void* const* d_in, const int* in_sizes, int n_in,
                              void* d_out, int out_size, void* d_ws, size_t ws_size,
                              hipStream_t stream) {
  const float* vel   = (const float*)d_in[0];
  const float* W_ih  = (const float*)d_in[1];
  const float* W_hh  = (const float*)d_in[2];
  const float* b_ih  = (const float*)d_in[3];
  const float* b_hh  = (const float*)d_in[4];
  const float* W_out = (const float*)d_in[5];
  const float* b_out = (const float*)d_in[6];

  float* pos = (float*)d_out;              // [B,T,2]
  float* u   = pos + (size_t)BB * TT * 2;  // [B,T,H]

  // ws: pub = 2 parities x 8 cohorts x 2 halves x 2048 tagged u64 = 512 KB.
  u64* pub = (u64*)d_ws;

  init_kernel<<<256, 256, 0, stream>>>(pub);  // zero all tags each launch
  rnn_kernel<<<8, 512, 0, stream>>>(vel, W_ih, W_hh, b_ih, b_hh, u, pub);
  pos_kernel<<<(BB * TT) / 4, 256, 0, stream>>>(u, W_out, b_out, pos);
}

// Round 9
// 3402.788 us; speedup vs baseline: 1.7637x; 1.7637x over previous
//
#include <hip/hip_runtime.h>
#include <hip/hip_bf16.h>

// PathRNN: h_{t+1} = tanh(x_t + W_hh h_t), u = h, pos = u @ W_out^T
// B=128, T=1024, H=512.
// ONE COHORT PER CU — zero cross-CU communication (r5/r7/r8 all deadlocked on
// cross-XCD transport; r3/r4 showed IC RTT floors the step at ~2.2us).
// 8 WGs x 512 threads (8 waves); WG c owns batches c*16..+15; wave w owns
// output cols w*64..+63. W_hh bf16: k-tiles 0..12 in REGISTERS (208 VGPR/lane,
// 416 KB/CU), k-tiles 13..15 in LDS (96 KB, bank-uniform layout). h double-
// buffered in LDS (2 x 16 KB, r4-proven XOR swizzle). Per step: 28 b128 LDS
// reads + 64 MFMAs per wave, fused tanh epilogue, ONE __syncthreads.
// Step critical path is intra-CU LDS pipe (~2000 cyc) — deterministic,
// no atomics, no workspace, graph-replay trivially safe.

#define TT 1024
#define BB 128
#define HH 512

typedef short s16x8 __attribute__((ext_vector_type(8)));
typedef float f32x4 __attribute__((ext_vector_type(4)));
typedef unsigned int uint;
typedef unsigned short ushort_t;

#define MFMA_B16(a, b, c) __builtin_amdgcn_mfma_f32_16x16x32_bf16((a), (b), (c), 0, 0, 0)

static __device__ __forceinline__ ushort_t bf16_rne(float f) {
  uint u = __float_as_uint(f);
  u += 0x7fffu + ((u >> 16) & 1u);  // round-to-nearest-even
  return (ushort_t)(u >> 16);
}

static __device__ __forceinline__ float tanh_fast(float z) {
  float e = __expf(2.0f * z);
  return 1.0f - 2.0f * __builtin_amdgcn_rcpf(e + 1.0f);
}

static __device__ __forceinline__ s16x8 packW(const float* wp) {
  float4 lo = *(const float4*)wp;
  float4 hi = *(const float4*)(wp + 4);
  s16x8 s;
  s[0] = (short)bf16_rne(lo.x); s[1] = (short)bf16_rne(lo.y);
  s[2] = (short)bf16_rne(lo.z); s[3] = (short)bf16_rne(lo.w);
  s[4] = (short)bf16_rne(hi.x); s[5] = (short)bf16_rne(hi.y);
  s[6] = (short)bf16_rne(hi.z); s[7] = (short)bf16_rne(hi.w);
  return s;
}

__global__ __launch_bounds__(512, 2) void rnn_kernel(
    const float* __restrict__ vel, const float* __restrict__ W_ih,
    const float* __restrict__ W_hh, const float* __restrict__ b_ih,
    const float* __restrict__ b_hh, float* __restrict__ u_out) {
  // LDS 128 KiB total:
  //   @0     : h dbuf [buf 2][row 16][col 512] bf16, byte ^ ((row&7)<<4) swizzle
  //   @32768 : W tail [kt 3][kg 4][n 512] x 16 B  (bank-group = n&7 -> uniform)
  __shared__ uint4 lds_mem[8192];
  char* hlds = (char*)lds_mem;

  const int tid = threadIdx.x;     // 0..511
  const int lane = tid & 63;
  const int w = tid >> 6;          // wave 0..7 -> 64-col strip
  const int c = blockIdx.x;        // cohort 0..7 (batches c*16..+15)
  const int l15 = lane & 15;
  const int kg = lane >> 4;        // 0..3
  const int n0w = w * 64;
  const uint swz = ((uint)l15 & 7u) << 4;

  // ---- one-time: W_hh k-tiles 0..12 -> registers (4 n-tiles x 13 kt) ----
  s16x8 wreg[4][13];
#pragma unroll
  for (int nt = 0; nt < 4; ++nt) {
    const float* wb = W_hh + (size_t)(n0w + nt * 16 + l15) * HH + kg * 8;
#pragma unroll
    for (int kt = 0; kt < 13; ++kt) wreg[nt][kt] = packW(wb + kt * 32);
  }

  // ---- one-time: W_hh k-tiles 13..15 -> LDS (thread tid fills col n=tid) ----
#pragma unroll
  for (int kti = 0; kti < 3; ++kti)
#pragma unroll
    for (int kq = 0; kq < 4; ++kq) {
      s16x8 s = packW(W_hh + (size_t)tid * HH + 416 + kti * 32 + kq * 8);
      *(s16x8*)(hlds + 32768 + (((kti * 4 + kq) * 512 + tid) << 4)) = s;
    }

  // ---- input-projection coefficients ----
  float wihA[4], wihB[4], bsv[4];
#pragma unroll
  for (int nt = 0; nt < 4; ++nt) {
    int n = n0w + nt * 16 + l15;
    wihA[nt] = W_ih[n * 2 + 0];
    wihB[nt] = W_ih[n * 2 + 1];
    bsv[nt] = b_ih[n] + b_hh[n];
  }

  // ---- zero h buf 0 (h_0 = 0): 16 KB / 512 threads ----
  {
    uint4 z = {0u, 0u, 0u, 0u};
    *(uint4*)(hlds + tid * 32) = z;
    *(uint4*)(hlds + tid * 32 + 16) = z;
  }
  __syncthreads();

  const f32x4 z4 = {0.f, 0.f, 0.f, 0.f};
  const bool odd = (l15 & 1) != 0;
  const uint rowbase = (uint)(kg * 4) + (odd ? 2u : 0u);
  const uint aInv = (uint)l15 * 1024u + (uint)kg * 16u;

  for (int t = 0; t < TT; ++t) {
    const int cur = t & 1;
    const int nxt = cur ^ 1;
    f32x4 acc0 = z4, acc1 = z4, acc2 = z4, acc3 = z4;
    const uint ab = (uint)cur * 16384u + aInv;

    // ---- register-resident K: 13 k-tiles x 4 n-tiles ----
#pragma unroll
    for (int kt = 0; kt < 13; ++kt) {
      s16x8 a = *(const s16x8*)(hlds + ((ab + (uint)(kt * 64)) ^ swz));
      acc0 = MFMA_B16(a, wreg[0][kt], acc0);
      acc1 = MFMA_B16(a, wreg[1][kt], acc1);
      acc2 = MFMA_B16(a, wreg[2][kt], acc2);
      acc3 = MFMA_B16(a, wreg[3][kt], acc3);
    }
    // ---- LDS-resident K tail: 3 k-tiles x 4 n-tiles ----
#pragma unroll
    for (int kti = 0; kti < 3; ++kti) {
      s16x8 a = *(const s16x8*)(hlds + ((ab + (uint)((13 + kti) * 64)) ^ swz));
      const uint wbase =
          32768u + (uint)(((kti * 4 + kg) * 512 + n0w + l15) << 4);
      s16x8 w0 = *(const s16x8*)(hlds + wbase);
      s16x8 w1 = *(const s16x8*)(hlds + wbase + 256);
      s16x8 w2 = *(const s16x8*)(hlds + wbase + 512);
      s16x8 w3 = *(const s16x8*)(hlds + wbase + 768);
      acc0 = MFMA_B16(a, w0, acc0);
      acc1 = MFMA_B16(a, w1, acc1);
      acc2 = MFMA_B16(a, w2, acc2);
      acc3 = MFMA_B16(a, w3, acc3);
    }

    // vel for this step (L2-resident; issued under MFMA drain)
    float2 v[4];
#pragma unroll
    for (int r = 0; r < 4; ++r)
      v[r] = *(const float2*)(vel + ((size_t)(c * 16 + kg * 4 + r) * TT + t) * 2);

    // ---- epilogue: x + tanh, u store, pack col-pairs, h[nxt] LDS write ----
    const uint ldsb = (uint)nxt * 16384u;
#pragma unroll
    for (int nt = 0; nt < 4; ++nt) {
      f32x4 acc = nt == 0 ? acc0 : nt == 1 ? acc1 : nt == 2 ? acc2 : acc3;
      ushort_t hb[4];
#pragma unroll
      for (int r = 0; r < 4; ++r) {
        float x = fmaf(v[r].x, wihA[nt], fmaf(v[r].y, wihB[nt], bsv[nt]));
        float uval = tanh_fast(x + acc[r]);
        __builtin_nontemporal_store(
            uval, u_out + ((size_t)(c * 16 + kg * 4 + r) * TT + t) * HH +
                      n0w + nt * 16 + l15);
        hb[r] = bf16_rne(uval);
      }
      uint a01p = (uint)hb[0] | ((uint)hb[1] << 16);
      uint a23p = (uint)hb[2] | ((uint)hb[3] << 16);
      uint b01p = __shfl_xor(a01p, 1);
      uint b23p = __shfl_xor(a23p, 1);
      uint eP = odd ? b23p : a01p;  // even col, rows (rowbase, rowbase+1)
      uint oP = odd ? a23p : b01p;  // odd col
      uint pr0 = (eP & 0xFFFFu) | (oP << 16);
      uint pr1 = (eP >> 16) | (oP & 0xFFFF0000u);
      uint cb = (uint)(n0w + nt * 16 + (l15 & ~1)) * 2u;
      *(uint*)(hlds + ((ldsb + rowbase * 1024u + cb) ^
                       ((rowbase & 7u) << 4))) = pr0;
      *(uint*)(hlds + ((ldsb + (rowbase + 1) * 1024u + cb) ^
                       (((rowbase + 1) & 7u) << 4))) = pr1;
    }
    __syncthreads();  // h_{t+1} assembled; also fences next step's buf reuse
  }
}

// pos[b,t,:] = u[b,t,:] @ W_out^T + b_out ; one wave per (b,t) row, BW-bound.
__global__ __launch_bounds__(256) void pos_kernel(const float* __restrict__ u,
                                                  const float* __restrict__ W_out,
                                                  const float* __restrict__ b_out,
                                                  float* __restrict__ pos) {
  int row = blockIdx.x * 4 + (threadIdx.x >> 6);
  int lane = threadIdx.x & 63;
  const float* ur = u + (size_t)row * HH + lane * 8;
  float4 u0 = *(const float4*)ur;
  float4 u1 = *(const float4*)(ur + 4);
  float4 w00 = *(const float4*)(W_out + lane * 8);
  float4 w01 = *(const float4*)(W_out + lane * 8 + 4);
  float4 w10 = *(const float4*)(W_out + HH + lane * 8);
  float4 w11 = *(const float4*)(W_out + HH + lane * 8 + 4);
  float p0 = u0.x * w00.x + u0.y * w00.y + u0.z * w00.z + u0.w * w00.w +
             u1.x * w01.x + u1.y * w01.y + u1.z * w01.z + u1.w * w01.w;
  float p1 = u0.x * w10.x + u0.y * w10.y + u0.z * w10.z + u0.w * w10.w +
             u1.x * w11.x + u1.y * w11.y + u1.z * w11.z + u1.w * w11.w;
#pragma unroll
  for (int off = 32; off; off >>= 1) {
    p0 += __shfl_xor(p0, off);
    p1 += __shfl_xor(p1, off);
  }
  if (lane == 0) {
    pos[(size_t)row * 2 + 0] = p0 + b_out[0];
    pos[(size_t)row * 2 + 1] = p1 + b_out[1];
  }
}

extern "C" void kernel_launch(void* const* d_in, const int* in_sizes, int n_in,
                              void* d_out, int out_size, void* d_ws, size_t ws_size,
                              hipStream_t stream) {
  const float* vel   = (const float*)d_in[0];
  const float* W_ih  = (const float*)d_in[1];
  const float* W_hh  = (const float*)d_in[2];
  const float* b_ih  = (const float*)d_in[3];
  const float* b_hh  = (const float*)d_in[4];
  const float* W_out = (const float*)d_in[5];
  const float* b_out = (const float*)d_in[6];

  float* pos = (float*)d_out;              // [B,T,2]
  float* u   = pos + (size_t)BB * TT * 2;  // [B,T,H]

  // No workspace, no init kernel, no inter-WG state: deterministic by design.
  rnn_kernel<<<8, 512, 0, stream>>>(vel, W_ih, W_hh, b_ih, b_hh, u);
  pos_kernel<<<(BB * TT) / 4, 256, 0, stream>>>(u, W_out, b_out, pos);
}

// Round 10
// 2685.238 us; speedup vs baseline: 2.2350x; 1.2672x over previous
//
#include <hip/hip_runtime.h>
#include <hip/hip_bf16.h>

// PathRNN: h_{t+1} = tanh(x_t + W_hh h_t), u = h, pos = u @ W_out^T
// B=128, T=1024, H=512.
// ONE COHORT PER CU (8 WGs x 512 thr, 8 waves x 64 cols). Zero cross-CU comm.
// W_hh bf16: kt 0..11 in registers (192 VGPR/lane), kt 12..15 in LDS (128 KB).
// h SINGLE-buffered in LDS (16 KB) with two raw s_barriers per step:
//   BAR1 (no waitcnt: MFMA reg-deps cover read completion) separates the
//   read phase from h-overwrite; BAR2 (lgkmcnt(0) only) publishes h(t+1).
//   No vmcnt drain per step -> u-stores stay fire-and-forget.
// ALL hot-loop addresses are static-base + immediate (A even/odd pre-XOR'd
// bases; W-tail [kg][kti][n] layout; u/vel via uniform ptr + static voffset).

#define TT 1024
#define BB 128
#define HH 512

typedef short s16x8 __attribute__((ext_vector_type(8)));
typedef float f32x4 __attribute__((ext_vector_type(4)));
typedef unsigned int uint;
typedef unsigned short ushort_t;

#define MFMA_B16(a, b, c) __builtin_amdgcn_mfma_f32_16x16x32_bf16((a), (b), (c), 0, 0, 0)

static __device__ __forceinline__ ushort_t bf16_rne(float f) {
  uint u = __float_as_uint(f);
  u += 0x7fffu + ((u >> 16) & 1u);
  return (ushort_t)(u >> 16);
}

static __device__ __forceinline__ uint cvt_pk_bf16(float lo, float hi) {
  uint r;
  asm("v_cvt_pk_bf16_f32 %0, %1, %2" : "=v"(r) : "v"(lo), "v"(hi));
  return r;  // lo16 = bf16(lo), hi16 = bf16(hi), RNE
}

static __device__ __forceinline__ float tanh_fast(float z) {
  float e = __expf(2.0f * z);
  return 1.0f - 2.0f * __builtin_amdgcn_rcpf(e + 1.0f);
}

static __device__ __forceinline__ s16x8 packW(const float* wp) {
  float4 lo = *(const float4*)wp;
  float4 hi = *(const float4*)(wp + 4);
  s16x8 s;
  s[0] = (short)bf16_rne(lo.x); s[1] = (short)bf16_rne(lo.y);
  s[2] = (short)bf16_rne(lo.z); s[3] = (short)bf16_rne(lo.w);
  s[4] = (short)bf16_rne(hi.x); s[5] = (short)bf16_rne(hi.y);
  s[6] = (short)bf16_rne(hi.z); s[7] = (short)bf16_rne(hi.w);
  return s;
}

__global__ __launch_bounds__(512, 2) void rnn_kernel(
    const float* __restrict__ vel, const float* __restrict__ W_ih,
    const float* __restrict__ W_hh, const float* __restrict__ b_ih,
    const float* __restrict__ b_hh, float* __restrict__ u_out) {
  // LDS 144 KiB:
  //   @0      h [row 16][col 512] bf16, byte ^ ((row&7)<<4)   (16 KiB, single)
  //   @16384  W tail [kg 4][kti 4][n 512] x 16 B              (128 KiB)
  __shared__ uint4 lds_mem[9216];  // 147456 B
  char* hlds = (char*)lds_mem;

  const int tid = threadIdx.x;   // 0..511
  const int lane = tid & 63;
  const int w = tid >> 6;        // wave 0..7 -> 64-col strip
  const int c = blockIdx.x;      // cohort 0..7
  const int l15 = lane & 15;
  const int kg = lane >> 4;      // 0..3
  const int n0w = w * 64;

  // ---- one-time: W_hh kt 0..11 -> registers ----
  s16x8 wreg[4][12];
#pragma unroll
  for (int nt = 0; nt < 4; ++nt) {
    const float* wb = W_hh + (size_t)(n0w + nt * 16 + l15) * HH + kg * 8;
#pragma unroll
    for (int kt = 0; kt < 12; ++kt) wreg[nt][kt] = packW(wb + kt * 32);
  }

  // ---- one-time: W_hh kt 12..15 -> LDS [kg][kti][n]*16B ----
#pragma unroll
  for (int kti = 0; kti < 4; ++kti)
#pragma unroll
    for (int kq = 0; kq < 4; ++kq) {
      s16x8 s = packW(W_hh + (size_t)tid * HH + (12 + kti) * 32 + kq * 8);
      *(s16x8*)(hlds + 16384 + (kq * 4 + kti) * 8192 + tid * 16) = s;
    }

  // ---- input-projection coefficients (12 regs) ----
  float wihA[4], wihB[4], bsv[4];
#pragma unroll
  for (int nt = 0; nt < 4; ++nt) {
    int n = n0w + nt * 16 + l15;
    wihA[nt] = W_ih[n * 2 + 0];
    wihB[nt] = W_ih[n * 2 + 1];
    bsv[nt] = b_ih[n] + b_hh[n];
  }

  // ---- zero h (h_0 = 0): 16 KB / 512 threads ----
  {
    uint4 z = {0u, 0u, 0u, 0u};
    *(uint4*)(hlds + tid * 32) = z;
    *(uint4*)(hlds + tid * 32 + 16) = z;
  }
  __syncthreads();

  // ---- static addresses ----
  const uint aswz = ((uint)l15 & 7u) << 4;
  const uint abase = (uint)l15 * 1024u + (uint)kg * 16u;
  const char* pAe = hlds + (abase ^ aswz);          // even kt: + (kt>>1)*128
  const char* pAo = hlds + ((abase + 64u) ^ aswz);  // odd  kt: + (kt>>1)*128
  const char* pW = hlds + 16384 + kg * 32768 + (n0w + l15) * 16;  // + kti*8192 + nt*256

  const bool odd = (l15 & 1) != 0;
  const uint rowb0 = (uint)(kg * 4) + (odd ? 2u : 0u);
  const uint rowb1 = rowb0 + 1u;
  const uint wr0 = rowb0 * 1024u + (uint)(n0w + (l15 & ~1)) * 2u;  // linear
  const uint wr1 = rowb1 * 1024u + (uint)(n0w + (l15 & ~1)) * 2u;
  const uint swz0 = (rowb0 & 7u) << 4;
  const uint swz1 = (rowb1 & 7u) << 4;

  uint uoff[4], voff[4];
#pragma unroll
  for (int r = 0; r < 4; ++r) {
    uint row = (uint)(c * 16 + kg * 4 + r);
    uoff[r] = row * (uint)(TT * HH) + (uint)(n0w + l15);  // element index
    voff[r] = row * (uint)(TT * 2);
  }

#define LDA(kt) ((kt & 1) ? *(const s16x8*)(pAo + ((kt) >> 1) * 128) \
                          : *(const s16x8*)(pAe + ((kt) >> 1) * 128))

  const f32x4 z4 = {0.f, 0.f, 0.f, 0.f};

  for (int t = 0; t < TT; ++t) {
    // vel loads (uniform base + static voffset -> saddr form)
    const float* vb = vel + t * 2;
    float2 v0 = *(const float2*)(vb + voff[0]);
    float2 v1 = *(const float2*)(vb + voff[1]);
    float2 v2 = *(const float2*)(vb + voff[2]);
    float2 v3 = *(const float2*)(vb + voff[3]);

    f32x4 acc0 = z4, acc1 = z4, acc2 = z4, acc3 = z4;

    // ---- K loop: 12 reg-kt + 4 LDS-kt, A prefetched one tile ahead ----
    s16x8 aF = LDA(0);
#pragma unroll
    for (int kt = 0; kt < 16; ++kt) {
      s16x8 aN;
      if (kt < 15) aN = LDA(kt + 1);
      s16x8 b0, b1, b2, b3;
      if (kt < 12) {
        b0 = wreg[0][kt]; b1 = wreg[1][kt]; b2 = wreg[2][kt]; b3 = wreg[3][kt];
      } else {
        const char* wp = pW + (kt - 12) * 8192;
        b0 = *(const s16x8*)(wp);
        b1 = *(const s16x8*)(wp + 256);
        b2 = *(const s16x8*)(wp + 512);
        b3 = *(const s16x8*)(wp + 768);
      }
      acc0 = MFMA_B16(aF, b0, acc0);
      acc1 = MFMA_B16(aF, b1, acc1);
      acc2 = MFMA_B16(aF, b2, acc2);
      acc3 = MFMA_B16(aF, b3, acc3);
      aF = aN;
    }

    // ---- epilogue: x + tanh, u-store (no drain), pack col-pairs ----
    float* ub = u_out + (size_t)t * HH;  // uniform part
    uint pr0v[4], pr1v[4];
#pragma unroll
    for (int nt = 0; nt < 4; ++nt) {
      f32x4 acc = (nt == 0) ? acc0 : (nt == 1) ? acc1 : (nt == 2) ? acc2 : acc3;
      float uvr[4];
      float2 vv[4] = {v0, v1, v2, v3};
#pragma unroll
      for (int r = 0; r < 4; ++r) {
        float x = fmaf(vv[r].x, wihA[nt], fmaf(vv[r].y, wihB[nt], bsv[nt]));
        uvr[r] = tanh_fast(x + acc[r]);
        __builtin_nontemporal_store(uvr[r], ub + uoff[r] + nt * 16);
      }
      uint a01 = cvt_pk_bf16(uvr[0], uvr[1]);
      uint a23 = cvt_pk_bf16(uvr[2], uvr[3]);
      uint b01 = __shfl_xor(a01, 1);
      uint b23 = __shfl_xor(a23, 1);
      uint eP = odd ? b23 : a01;  // even col, rows (rowb0, rowb0+1)
      uint oP = odd ? a23 : b01;  // odd col
      pr0v[nt] = (eP & 0xFFFFu) | (oP << 16);
      pr1v[nt] = (eP >> 16) | (oP & 0xFFFF0000u);
    }

    // BAR1: every wave done READING h(t). No waitcnt needed: all ds_reads
    // were consumed by MFMAs (compiler-inserted lgkmcnt before use).
    asm volatile("s_barrier" ::: "memory");

#pragma unroll
    for (int nt = 0; nt < 4; ++nt) {
      *(uint*)(hlds + ((wr0 + (uint)(nt * 32)) ^ swz0)) = pr0v[nt];
      *(uint*)(hlds + ((wr1 + (uint)(nt * 32)) ^ swz1)) = pr1v[nt];
    }
    asm volatile("s_waitcnt lgkmcnt(0)" ::: "memory");
    __builtin_amdgcn_sched_barrier(0);
    // BAR2: h(t+1) fully visible. vmcnt NOT drained (u-stores in flight).
    asm volatile("s_barrier" ::: "memory");
  }
}

// pos[b,t,:] = u[b,t,:] @ W_out^T + b_out ; one wave per (b,t) row, BW-bound.
__global__ __launch_bounds__(256) void pos_kernel(const float* __restrict__ u,
                                                  const float* __restrict__ W_out,
                                                  const float* __restrict__ b_out,
                                                  float* __restrict__ pos) {
  int row = blockIdx.x * 4 + (threadIdx.x >> 6);
  int lane = threadIdx.x & 63;
  const float* ur = u + (size_t)row * HH + lane * 8;
  float4 u0 = *(const float4*)ur;
  float4 u1 = *(const float4*)(ur + 4);
  float4 w00 = *(const float4*)(W_out + lane * 8);
  float4 w01 = *(const float4*)(W_out + lane * 8 + 4);
  float4 w10 = *(const float4*)(W_out + HH + lane * 8);
  float4 w11 = *(const float4*)(W_out + HH + lane * 8 + 4);
  float p0 = u0.x * w00.x + u0.y * w00.y + u0.z * w00.z + u0.w * w00.w +
             u1.x * w01.x + u1.y * w01.y + u1.z * w01.z + u1.w * w01.w;
  float p1 = u0.x * w10.x + u0.y * w10.y + u0.z * w10.z + u0.w * w10.w +
             u1.x * w11.x + u1.y * w11.y + u1.z * w11.z + u1.w * w11.w;
#pragma unroll
  for (int off = 32; off; off >>= 1) {
    p0 += __shfl_xor(p0, off);
    p1 += __shfl_xor(p1, off);
  }
  if (lane == 0) {
    pos[(size_t)row * 2 + 0] = p0 + b_out[0];
    pos[(size_t)row * 2 + 1] = p1 + b_out[1];
  }
}

extern "C" void kernel_launch(void* const* d_in, const int* in_sizes, int n_in,
                              void* d_out, int out_size, void* d_ws, size_t ws_size,
                              hipStream_t stream) {
  const float* vel   = (const float*)d_in[0];
  const float* W_ih  = (const float*)d_in[1];
  const float* W_hh  = (const float*)d_in[2];
  const float* b_ih  = (const float*)d_in[3];
  const float* b_hh  = (const float*)d_in[4];
  const float* W_out = (const float*)d_in[5];
  const float* b_out = (const float*)d_in[6];

  float* pos = (float*)d_out;              // [B,T,2]
  float* u   = pos + (size_t)BB * TT * 2;  // [B,T,H]

  // No workspace, no inter-WG state: deterministic, replay-safe by design.
  rnn_kernel<<<8, 512, 0, stream>>>(vel, W_ih, W_hh, b_ih, b_hh, u);
  pos_kernel<<<(BB * TT) / 4, 256, 0, stream>>>(u, W_out, b_out, pos);
}